// Round 1
// baseline (976.368 us; speedup 1.0000x reference)
//
#include <hip/hip_runtime.h>
#include <stdint.h>

// HybridCodebook forward, MFMA edition.
//   xn = normalize(x); cb = [normalize(sem); normalize(learn)]
//   logits = xn @ cb^T ; indices = argmax ; z_q = cb[indices]; losses.
// Outputs (f32, flat): logits [8192*8320], indices [8192], z_q [8192*1024],
//   z_q_st [8192*1024], vq_loss, commitment_loss, quant_loss.
//
// R3 change: replace fp32 VALU GEMM (887 us theoretical floor, 2055 us measured)
// with fp16 2-split MFMA GEMM: x = hi+lo (11+11 mantissa bits), dot = hi*hi +
// hi*lo + lo*hi (drop lo*lo ~ 2^-22 rel => logits err ~1e-7). 3x139.6 = 419
// GFLOP f16 at m97-structure (~900 TF) => ~465 us GEMM vs 2055 us total before.
//
// Split staging: x hi/lo EXACTLY fills o_zq region (8192*1024*2*2 B = 33.55 MB),
// sem hi/lo EXACTLY fills o_zst region; both are only overwritten by k_epilogue
// AFTER the GEMM. Learnable hi/lo (512 KB) + norms/keys/accum live in d_ws
// (total ~656 KB; prior session proved ws >= ~98 KB, assuming >= 1 MB here).

#define N_TOK   8192
#define DIM     1024
#define N_SEM   8192
#define N_LEARN 128
#define N_CODE  (N_SEM + N_LEARN)   // 8320

typedef _Float16 f16;
typedef _Float16 f16x4 __attribute__((ext_vector_type(4)));
typedef _Float16 f16x8 __attribute__((ext_vector_type(8)));
typedef float    f32x4 __attribute__((ext_vector_type(4)));

// ---- K0: zero argmax keys + loss accumulators (ws is poisoned 0xAA) ----
__global__ void k_init(unsigned long long* keys, float* accum) {
    int i = blockIdx.x * blockDim.x + threadIdx.x;
    if (i < N_TOK) keys[i] = 0ULL;
    if (i < 4) accum[i] = 0.f;
}

// ---- K1: per-row inverse L2 norm + fp16 hi/lo split write ----
__global__ __launch_bounds__(256) void k_norm_split(
    const float* __restrict__ in, float* __restrict__ invn,
    f16* __restrict__ hi, f16* __restrict__ lo)
{
    const int row = blockIdx.x;
    const int t = threadIdx.x;
    float4 v = ((const float4*)(in + (size_t)row * DIM))[t];
    float ss = v.x*v.x + v.y*v.y + v.z*v.z + v.w*v.w;
    #pragma unroll
    for (int off = 32; off > 0; off >>= 1) ss += __shfl_xor(ss, off);
    __shared__ float red[4];
    if ((t & 63) == 0) red[t >> 6] = ss;

    f16 h0 = (f16)v.x, h1 = (f16)v.y, h2 = (f16)v.z, h3 = (f16)v.w;
    f16x4 hv = {h0, h1, h2, h3};
    f16x4 lv = {(f16)(v.x - (float)h0), (f16)(v.y - (float)h1),
                (f16)(v.z - (float)h2), (f16)(v.w - (float)h3)};
    ((f16x4*)(hi + (size_t)row * DIM))[t] = hv;
    ((f16x4*)(lo + (size_t)row * DIM))[t] = lv;

    __syncthreads();
    if (t == 0) {
        float tot = red[0] + red[1] + red[2] + red[3];
        invn[row] = 1.f / fmaxf(sqrtf(tot), 1e-8f);
    }
}

// ---- K2: fp16-split MFMA GEMM + scaled f32 logits store + packed argmax ----
#define BM 128
#define BN 128
#define BK 32

__device__ __forceinline__ void gload16(const void* g, void* l) {
    __builtin_amdgcn_global_load_lds(
        (const __attribute__((address_space(1))) void*)g,
        (__attribute__((address_space(3))) void*)l, 16, 0, 0);
}

__global__ __launch_bounds__(256) void k_gemm_mfma(
    const f16* __restrict__ xHi,  const f16* __restrict__ xLo,
    const f16* __restrict__ semHi, const f16* __restrict__ semLo,
    const f16* __restrict__ lrnHi, const f16* __restrict__ lrnLo,
    const float* __restrict__ invnx, const float* __restrict__ invnb,
    float* __restrict__ logits, unsigned long long* __restrict__ keys)
{
    // LDS tiles, row-major [rows][BK] f16 (row stride 64 B: fragment b128 reads
    // land uniformly on all 32 banks -> at the 1024B/128B wave-b128 floor).
    __shared__ __align__(16) f16 sAh[BM * BK];
    __shared__ __align__(16) f16 sAl[BM * BK];
    __shared__ __align__(16) f16 sBh[BN * BK];
    __shared__ __align__(16) f16 sBl[BN * BK];

    const int t    = threadIdx.x;
    const int lane = t & 63;
    const int wid  = t >> 6;              // 4 waves, 2x2 over 128x128
    const int row0 = blockIdx.x * BM;
    const int col0 = blockIdx.y * BN;
    const int wm   = (wid >> 1) * 64;
    const int wn   = (wid & 1) * 64;

    // N_SEM % BN == 0, so each block's column tile is purely sem or purely lrn.
    const f16* bh; const f16* bl;
    if (col0 < N_SEM) { bh = semHi + (size_t)col0 * DIM;
                        bl = semLo + (size_t)col0 * DIM; }
    else              { bh = lrnHi + (size_t)(col0 - N_SEM) * DIM;
                        bl = lrnLo + (size_t)(col0 - N_SEM) * DIM; }
    const f16* ah = xHi + (size_t)row0 * DIM;
    const f16* al = xLo + (size_t)row0 * DIM;

    // staging: chunk c = 16 B; c covers (tile row c>>2, k sub-chunk (c&3)*8).
    // LDS linear order == lane order (global_load_lds dest = base + lane*16).
    const int sr = t >> 2;
    const int sk = (t & 3) * 8;
    const size_t g0 = (size_t)sr * DIM + sk;
    const size_t g1 = g0 + (size_t)64 * DIM;   // chunk t+256 -> row sr+64
    f16* lA0  = sAh + t * 8;  f16* lA1  = sAh + t * 8 + 2048;
    f16* lAl0 = sAl + t * 8;  f16* lAl1 = sAl + t * 8 + 2048;
    f16* lB0  = sBh + t * 8;  f16* lB1  = sBh + t * 8 + 2048;
    f16* lBl0 = sBl + t * 8;  f16* lBl1 = sBl + t * 8 + 2048;

    f32x4 acc[4][4];
    #pragma unroll
    for (int i = 0; i < 4; ++i)
        #pragma unroll
        for (int j = 0; j < 4; ++j) acc[i][j] = (f32x4)0.f;

    // fragment read addresses: lane holds A[m][k], m = lane&15,
    // k = (lane>>4)*8 + j (contiguous 8 f16 = one b128)
    const int fr = lane & 15;
    const int fg = lane >> 4;
    const f16* rAh = sAh + (wm + fr) * BK + fg * 8;
    const f16* rAl = sAl + (wm + fr) * BK + fg * 8;
    const f16* rBh = sBh + (wn + fr) * BK + fg * 8;
    const f16* rBl = sBl + (wn + fr) * BK + fg * 8;

    #pragma unroll 1
    for (int k0 = 0; k0 < DIM; k0 += BK) {
        gload16(ah + g0 + k0, lA0);
        gload16(ah + g1 + k0, lA1);
        gload16(al + g0 + k0, lAl0);
        gload16(al + g1 + k0, lAl1);
        gload16(bh + g0 + k0, lB0);
        gload16(bh + g1 + k0, lB1);
        gload16(bl + g0 + k0, lBl0);
        gload16(bl + g1 + k0, lBl1);
        __syncthreads();   // drains vmcnt -> LDS tiles ready

        f16x8 aH[4], aL[4], bH[4], bL[4];
        #pragma unroll
        for (int f = 0; f < 4; ++f) {
            aH[f] = *(const f16x8*)(rAh + f * 16 * BK);
            aL[f] = *(const f16x8*)(rAl + f * 16 * BK);
            bH[f] = *(const f16x8*)(rBh + f * 16 * BK);
            bL[f] = *(const f16x8*)(rBl + f * 16 * BK);
        }
        #pragma unroll
        for (int i = 0; i < 4; ++i)
            #pragma unroll
            for (int j = 0; j < 4; ++j) {
                acc[i][j] = __builtin_amdgcn_mfma_f32_16x16x32_f16(aH[i], bH[j], acc[i][j], 0, 0, 0);
                acc[i][j] = __builtin_amdgcn_mfma_f32_16x16x32_f16(aH[i], bL[j], acc[i][j], 0, 0, 0);
                acc[i][j] = __builtin_amdgcn_mfma_f32_16x16x32_f16(aL[i], bH[j], acc[i][j], 0, 0, 0);
            }
        __syncthreads();   // protect single-buffered LDS
    }

    // epilogue: scale by invnx*invnb, store f32 logits, per-row packed argmax.
    // C/D layout (m89/m91-verified): col = lane&15 (fr), row = fg*4 + reg.
    float ibv[4];
    #pragma unroll
    for (int fn = 0; fn < 4; ++fn) ibv[fn] = invnb[col0 + wn + fn * 16 + fr];

    #pragma unroll
    for (int fm = 0; fm < 4; ++fm) {
        #pragma unroll
        for (int reg = 0; reg < 4; ++reg) {
            const int row = row0 + wm + fm * 16 + fg * 4 + reg;
            const float ia = invnx[row];
            float best = -3.4e38f; int bcol = 0;
            float* dst = logits + (size_t)row * N_CODE + col0 + wn + fr;
            #pragma unroll
            for (int fn = 0; fn < 4; ++fn) {
                float v = acc[fm][fn][reg] * (ia * ibv[fn]);
                dst[fn * 16] = v;
                int c = col0 + wn + fn * 16 + fr;
                if (v > best) { best = v; bcol = c; }
            }
            // reduce (best,bcol) across the 16 fr-lanes of this row
            #pragma unroll
            for (int off = 8; off > 0; off >>= 1) {
                float ov = __shfl_xor(best, off);
                int   oc = __shfl_xor(bcol, off);
                if (ov > best || (ov == best && oc < bcol)) { best = ov; bcol = oc; }
            }
            if (fr == 0) {
                unsigned int u = __float_as_uint(best);
                unsigned int s = (u & 0x80000000u) ? ~u : (u | 0x80000000u);
                unsigned long long key = ((unsigned long long)s << 14) |
                                         (unsigned long long)(16383 - bcol);
                atomicMax(keys + row, key);
            }
        }
    }
}

// ---- K3: per-token gather + cos-sim losses, one block per token ----
__global__ __launch_bounds__(256) void k_epilogue(
    const float* __restrict__ X,
    const float* __restrict__ SEM,
    const float* __restrict__ LRN,
    const float* __restrict__ invnx,
    const float* __restrict__ invnb,
    const unsigned long long* __restrict__ keys,
    float* __restrict__ o_idx,
    float* __restrict__ o_zq,
    float* __restrict__ o_zst,
    float* __restrict__ accum)
{
    const int tok = blockIdx.x;
    const int t = threadIdx.x;
    const int col = 16383 - (int)(keys[tok] & 16383ULL);
    const float ix = invnx[tok];
    const float ib = invnb[col];
    const float* crow = (col < N_SEM) ? (SEM + (size_t)col * DIM)
                                      : (LRN + (size_t)(col - N_SEM) * DIM);

    float4 xr = ((const float4*)(X + (size_t)tok * DIM))[t];
    float4 cr = ((const float4*)crow)[t];
    float4 xv; xv.x = xr.x*ix; xv.y = xr.y*ix; xv.z = xr.z*ix; xv.w = xr.w*ix;
    float4 zv; zv.x = cr.x*ib; zv.y = cr.y*ib; zv.z = cr.z*ib; zv.w = cr.w*ib;

    float d  = xv.x*zv.x + xv.y*zv.y + xv.z*zv.z + xv.w*zv.w;
    float nx = xv.x*xv.x + xv.y*xv.y + xv.z*xv.z + xv.w*xv.w;
    float nz = zv.x*zv.x + zv.y*zv.y + zv.z*zv.z + zv.w*zv.w;
    #pragma unroll
    for (int off = 32; off > 0; off >>= 1) {
        d  += __shfl_xor(d, off);
        nx += __shfl_xor(nx, off);
        nz += __shfl_xor(nz, off);
    }
    __shared__ float rd[4], rx[4], rz[4];
    if ((t & 63) == 0) { rd[t>>6] = d; rx[t>>6] = nx; rz[t>>6] = nz; }
    __syncthreads();

    float4 zs;
    zs.x = xv.x + (zv.x - xv.x);
    zs.y = xv.y + (zv.y - xv.y);
    zs.z = xv.z + (zv.z - xv.z);
    zs.w = xv.w + (zv.w - xv.w);
    ((float4*)o_zq)[(size_t)tok * 256 + t] = zv;
    ((float4*)o_zst)[(size_t)tok * 256 + t] = zs;

    if (t == 0) {
        float D  = rd[0]+rd[1]+rd[2]+rd[3];
        float NX = rx[0]+rx[1]+rx[2]+rx[3];
        float NZ = rz[0]+rz[1]+rz[2]+rz[3];
        float cs = D / (fmaxf(sqrtf(NX), 1e-8f) * fmaxf(sqrtf(NZ), 1e-8f));
        float per = 1.f - cs;
        o_idx[tok] = (float)col;
        atomicAdd(accum + 0, per);                 // commitment sum
        if (col >= N_SEM) {
            atomicAdd(accum + 1, per);             // vq sum
            atomicAdd(accum + 2, 1.f);             // learnable count
        }
    }
}

// ---- K4: finalize scalars ----
__global__ void k_final(const float* __restrict__ accum,
                        float* __restrict__ o_scal) {
    float commit = accum[0] / (float)N_TOK;
    float vq     = accum[1] / (accum[2] + 1e-6f);
    o_scal[0] = vq;
    o_scal[1] = commit;
    o_scal[2] = vq + 0.25f * commit;
}

extern "C" void kernel_launch(void* const* d_in, const int* in_sizes, int n_in,
                              void* d_out, int out_size, void* d_ws, size_t ws_size,
                              hipStream_t stream) {
    const float* x   = (const float*)d_in[0];   // [8192,1024] fp32
    const float* sem = (const float*)d_in[1];   // [8192,1024] fp32
    const float* lrn = (const float*)d_in[2];   // [128,1024]  fp32

    // ws: invnx[8192] | invnb[8320] | keys[8192] u64 | accum[4] | lrn hi/lo f16
    // total ~656 KB
    float* invnx = (float*)d_ws;
    float* invnb = invnx + N_TOK;
    unsigned long long* keys = (unsigned long long*)(invnb + N_CODE); // byte 66048, 8-aligned
    float* accum = (float*)(keys + N_TOK);
    f16* lrnHi = (f16*)(accum + 4);             // byte 131600, 16-aligned
    f16* lrnLo = lrnHi + (size_t)N_LEARN * DIM;

    float* out      = (float*)d_out;
    float* o_logits = out;                                  // 68,157,440 f32
    float* o_idx    = o_logits + (size_t)N_TOK * N_CODE;    // 8,192
    float* o_zq     = o_idx + N_TOK;                        // 8,388,608
    float* o_zst    = o_zq + (size_t)N_TOK * DIM;           // 8,388,608
    float* o_scal   = o_zst + (size_t)N_TOK * DIM;          // 3

    // split scratch aliased onto z_q / z_q_st (overwritten later by k_epilogue)
    f16* xHi   = (f16*)o_zq;                    // 8192*1024 f16
    f16* xLo   = xHi + (size_t)N_TOK * DIM;     //  = exactly o_zq's 33.55 MB
    f16* semHi = (f16*)o_zst;
    f16* semLo = semHi + (size_t)N_SEM * DIM;   //  = exactly o_zst's 33.55 MB

    k_init<<<(N_TOK + 255) / 256, 256, 0, stream>>>(keys, accum);
    k_norm_split<<<N_TOK,   256, 0, stream>>>(x,   invnx,         xHi,   xLo);
    k_norm_split<<<N_SEM,   256, 0, stream>>>(sem, invnb,         semHi, semLo);
    k_norm_split<<<N_LEARN, 256, 0, stream>>>(lrn, invnb + N_SEM, lrnHi, lrnLo);

    dim3 g2(N_TOK / BM, N_CODE / BN);   // 64 x 65
    k_gemm_mfma<<<g2, 256, 0, stream>>>(xHi, xLo, semHi, semLo, lrnHi, lrnLo,
                                        invnx, invnb, o_logits, keys);

    k_epilogue<<<N_TOK, 256, 0, stream>>>(x, sem, lrn, invnx, invnb, keys,
                                          o_idx, o_zq, o_zst, accum);
    k_final<<<1, 1, 0, stream>>>(accum, o_scal);
}

// Round 2
// 884.352 us; speedup vs baseline: 1.1040x; 1.1040x over previous
//
#include <hip/hip_runtime.h>
#include <stdint.h>

// HybridCodebook forward, MFMA edition, R2.
//   xn = normalize(x); cb = [normalize(sem); normalize(learn)]
//   logits = xn @ cb^T ; indices = argmax ; z_q = cb[indices]; losses.
// Outputs (f32, flat): logits [8192*8320], indices [8192], z_q [8192*1024],
//   z_q_st [8192*1024], vq_loss, commitment_loss, quant_loss.
//
// R2 changes vs R1 (976 us: GEMM 559 us + 417 us unaccounted):
//  (a) k_epilogue: removed 24.6K same-cache-line device atomicAdds (8192 blocks
//      x 3 adds to accum[0..2] -> serialized cross-XCD line ping-pong, theory
//      for the 417 us gap). Now writes per-token `per` to ws; single-block
//      k_final reduces 8192 values (~3 us).
//  (b) k_gemm_mfma: LDS XOR chunk-swizzle (T2). Row stride is 64B so 16-lane
//      b128 fragment reads hit 2 of 8 four-bank slots = 8-way conflict
//      (SQ_LDS_BANK_CONFLICT 3.4e7). Swizzle c' = c ^ ((row>>1)&3) spreads each
//      16-lane group over 8 slots x 2 lanes (2-way = free). Applied both-sides
//      (rule #21): pre-swizzled global_load_lds SOURCE + swizzled ds_read; LDS
//      dest stays linear.
//
// fp16 2-split numerics (hi+lo, drop lo*lo): logits err ~1e-7, absmax 4.9e-4
// measured-passing in R1. Split staging aliases output buffer: x hi/lo fills
// o_zq exactly, sem hi/lo fills o_zst exactly; both overwritten only by
// k_epilogue AFTER the GEMM.

#define N_TOK   8192
#define DIM     1024
#define N_SEM   8192
#define N_LEARN 128
#define N_CODE  (N_SEM + N_LEARN)   // 8320

typedef _Float16 f16;
typedef _Float16 f16x4 __attribute__((ext_vector_type(4)));
typedef _Float16 f16x8 __attribute__((ext_vector_type(8)));
typedef float    f32x4 __attribute__((ext_vector_type(4)));

// ---- K0: zero argmax keys (ws is poisoned 0xAA) ----
__global__ void k_init(unsigned long long* keys) {
    int i = blockIdx.x * blockDim.x + threadIdx.x;
    if (i < N_TOK) keys[i] = 0ULL;
}

// ---- K1: per-row inverse L2 norm + fp16 hi/lo split write ----
__global__ __launch_bounds__(256) void k_norm_split(
    const float* __restrict__ in, float* __restrict__ invn,
    f16* __restrict__ hi, f16* __restrict__ lo)
{
    const int row = blockIdx.x;
    const int t = threadIdx.x;
    float4 v = ((const float4*)(in + (size_t)row * DIM))[t];
    float ss = v.x*v.x + v.y*v.y + v.z*v.z + v.w*v.w;
    #pragma unroll
    for (int off = 32; off > 0; off >>= 1) ss += __shfl_xor(ss, off);
    __shared__ float red[4];
    if ((t & 63) == 0) red[t >> 6] = ss;

    f16 h0 = (f16)v.x, h1 = (f16)v.y, h2 = (f16)v.z, h3 = (f16)v.w;
    f16x4 hv = {h0, h1, h2, h3};
    f16x4 lv = {(f16)(v.x - (float)h0), (f16)(v.y - (float)h1),
                (f16)(v.z - (float)h2), (f16)(v.w - (float)h3)};
    ((f16x4*)(hi + (size_t)row * DIM))[t] = hv;
    ((f16x4*)(lo + (size_t)row * DIM))[t] = lv;

    __syncthreads();
    if (t == 0) {
        float tot = red[0] + red[1] + red[2] + red[3];
        invn[row] = 1.f / fmaxf(sqrtf(tot), 1e-8f);
    }
}

// ---- K2: fp16-split MFMA GEMM + scaled f32 logits store + packed argmax ----
#define BM 128
#define BN 128
#define BK 32

__device__ __forceinline__ void gload16(const void* g, void* l) {
    __builtin_amdgcn_global_load_lds(
        (const __attribute__((address_space(1))) void*)g,
        (__attribute__((address_space(3))) void*)l, 16, 0, 0);
}

__global__ __launch_bounds__(256) void k_gemm_mfma(
    const f16* __restrict__ xHi,  const f16* __restrict__ xLo,
    const f16* __restrict__ semHi, const f16* __restrict__ semLo,
    const f16* __restrict__ lrnHi, const f16* __restrict__ lrnLo,
    const float* __restrict__ invnx, const float* __restrict__ invnb,
    float* __restrict__ logits, unsigned long long* __restrict__ keys)
{
    // LDS tiles [128 rows][BK=32 f16] (64 B/row), linear for global_load_lds.
    __shared__ __align__(16) f16 sAh[BM * BK];
    __shared__ __align__(16) f16 sAl[BM * BK];
    __shared__ __align__(16) f16 sBh[BN * BK];
    __shared__ __align__(16) f16 sBl[BN * BK];

    const int t    = threadIdx.x;
    const int lane = t & 63;
    const int wid  = t >> 6;              // 4 waves, 2x2 over 128x128
    const int row0 = blockIdx.x * BM;
    const int col0 = blockIdx.y * BN;
    const int wm   = (wid >> 1) * 64;
    const int wn   = (wid & 1) * 64;

    // N_SEM % BN == 0, so each block's column tile is purely sem or purely lrn.
    const f16* bh; const f16* bl;
    if (col0 < N_SEM) { bh = semHi + (size_t)col0 * DIM;
                        bl = semLo + (size_t)col0 * DIM; }
    else              { bh = lrnHi + (size_t)(col0 - N_SEM) * DIM;
                        bl = lrnLo + (size_t)(col0 - N_SEM) * DIM; }
    const f16* ah = xHi + (size_t)row0 * DIM;
    const f16* al = xLo + (size_t)row0 * DIM;

    // Staging with pre-swizzled SOURCE (m173 pattern): LDS slot (row sr,
    // stored-chunk t&3) receives logical chunk (t&3)^((sr>>1)&3). Chunk = 8 f16
    // = 16 B. Rows sr and sr+64 share swizzle bits (64>>1 ≡ 0 mod 4).
    const int sr = t >> 2;                       // 0..63
    const int sc = (t & 3) ^ ((sr >> 1) & 3);    // logical chunk for this slot
    const size_t g0 = (size_t)sr * DIM + sc * 8;
    const size_t g1 = g0 + (size_t)64 * DIM;     // chunk t+256 -> row sr+64
    f16* lA0  = sAh + t * 8;  f16* lA1  = sAh + t * 8 + 2048;
    f16* lAl0 = sAl + t * 8;  f16* lAl1 = sAl + t * 8 + 2048;
    f16* lB0  = sBh + t * 8;  f16* lB1  = sBh + t * 8 + 2048;
    f16* lBl0 = sBl + t * 8;  f16* lBl1 = sBl + t * 8 + 2048;

    f32x4 acc[4][4];
    #pragma unroll
    for (int i = 0; i < 4; ++i)
        #pragma unroll
        for (int j = 0; j < 4; ++j) acc[i][j] = (f32x4)0.f;

    // Fragment reads: lane holds A[m][k], m = lane&15 (fr), k = fg*8+j.
    // Stored chunk for logical chunk fg at row (wm|wn)+fr is fg^((fr>>1)&3)
    // (wm,wn multiples of 64, f*16 rows preserve (row>>1)&3).
    const int fr  = lane & 15;
    const int fg  = lane >> 4;
    const int swz = fg ^ ((fr >> 1) & 3);
    const f16* rAh = sAh + (wm + fr) * BK + swz * 8;
    const f16* rAl = sAl + (wm + fr) * BK + swz * 8;
    const f16* rBh = sBh + (wn + fr) * BK + swz * 8;
    const f16* rBl = sBl + (wn + fr) * BK + swz * 8;

    #pragma unroll 1
    for (int k0 = 0; k0 < DIM; k0 += BK) {
        gload16(ah + g0 + k0, lA0);
        gload16(ah + g1 + k0, lA1);
        gload16(al + g0 + k0, lAl0);
        gload16(al + g1 + k0, lAl1);
        gload16(bh + g0 + k0, lB0);
        gload16(bh + g1 + k0, lB1);
        gload16(bl + g0 + k0, lBl0);
        gload16(bl + g1 + k0, lBl1);
        __syncthreads();   // drains vmcnt -> LDS tiles ready

        f16x8 aH[4], aL[4], bH[4], bL[4];
        #pragma unroll
        for (int f = 0; f < 4; ++f) {
            aH[f] = *(const f16x8*)(rAh + f * 16 * BK);
            aL[f] = *(const f16x8*)(rAl + f * 16 * BK);
            bH[f] = *(const f16x8*)(rBh + f * 16 * BK);
            bL[f] = *(const f16x8*)(rBl + f * 16 * BK);
        }
        #pragma unroll
        for (int i = 0; i < 4; ++i)
            #pragma unroll
            for (int j = 0; j < 4; ++j) {
                acc[i][j] = __builtin_amdgcn_mfma_f32_16x16x32_f16(aH[i], bH[j], acc[i][j], 0, 0, 0);
                acc[i][j] = __builtin_amdgcn_mfma_f32_16x16x32_f16(aH[i], bL[j], acc[i][j], 0, 0, 0);
                acc[i][j] = __builtin_amdgcn_mfma_f32_16x16x32_f16(aL[i], bH[j], acc[i][j], 0, 0, 0);
            }
        __syncthreads();   // protect single-buffered LDS
    }

    // epilogue: scale by invnx*invnb, store f32 logits, per-row packed argmax.
    // C/D layout (m89/m91-verified): col = lane&15 (fr), row = fg*4 + reg.
    float ibv[4];
    #pragma unroll
    for (int fn = 0; fn < 4; ++fn) ibv[fn] = invnb[col0 + wn + fn * 16 + fr];

    #pragma unroll
    for (int fm = 0; fm < 4; ++fm) {
        #pragma unroll
        for (int reg = 0; reg < 4; ++reg) {
            const int row = row0 + wm + fm * 16 + fg * 4 + reg;
            const float ia = invnx[row];
            float best = -3.4e38f; int bcol = 0;
            float* dst = logits + (size_t)row * N_CODE + col0 + wn + fr;
            #pragma unroll
            for (int fn = 0; fn < 4; ++fn) {
                float v = acc[fm][fn][reg] * (ia * ibv[fn]);
                dst[fn * 16] = v;
                int c = col0 + wn + fn * 16 + fr;
                if (v > best) { best = v; bcol = c; }
            }
            // reduce (best,bcol) across the 16 fr-lanes of this row
            #pragma unroll
            for (int off = 8; off > 0; off >>= 1) {
                float ov = __shfl_xor(best, off);
                int   oc = __shfl_xor(bcol, off);
                if (ov > best || (ov == best && oc < bcol)) { best = ov; bcol = oc; }
            }
            if (fr == 0) {
                unsigned int u = __float_as_uint(best);
                unsigned int s = (u & 0x80000000u) ? ~u : (u | 0x80000000u);
                unsigned long long key = ((unsigned long long)s << 14) |
                                         (unsigned long long)(16383 - bcol);
                atomicMax(keys + row, key);
            }
        }
    }
}

// ---- K3: per-token gather + cos-sim; per-token loss to ws (NO global atomics) ----
__global__ __launch_bounds__(256) void k_epilogue(
    const float* __restrict__ X,
    const float* __restrict__ SEM,
    const float* __restrict__ LRN,
    const float* __restrict__ invnx,
    const float* __restrict__ invnb,
    const unsigned long long* __restrict__ keys,
    float* __restrict__ o_idx,
    float* __restrict__ o_zq,
    float* __restrict__ o_zst,
    float* __restrict__ perTok)
{
    const int tok = blockIdx.x;
    const int t = threadIdx.x;
    const int col = 16383 - (int)(keys[tok] & 16383ULL);
    const float ix = invnx[tok];
    const float ib = invnb[col];
    const float* crow = (col < N_SEM) ? (SEM + (size_t)col * DIM)
                                      : (LRN + (size_t)(col - N_SEM) * DIM);

    float4 xr = ((const float4*)(X + (size_t)tok * DIM))[t];
    float4 cr = ((const float4*)crow)[t];
    float4 xv; xv.x = xr.x*ix; xv.y = xr.y*ix; xv.z = xr.z*ix; xv.w = xr.w*ix;
    float4 zv; zv.x = cr.x*ib; zv.y = cr.y*ib; zv.z = cr.z*ib; zv.w = cr.w*ib;

    float d  = xv.x*zv.x + xv.y*zv.y + xv.z*zv.z + xv.w*zv.w;
    float nx = xv.x*xv.x + xv.y*xv.y + xv.z*xv.z + xv.w*xv.w;
    float nz = zv.x*zv.x + zv.y*zv.y + zv.z*zv.z + zv.w*zv.w;
    #pragma unroll
    for (int off = 32; off > 0; off >>= 1) {
        d  += __shfl_xor(d, off);
        nx += __shfl_xor(nx, off);
        nz += __shfl_xor(nz, off);
    }
    __shared__ float rd[4], rx[4], rz[4];
    if ((t & 63) == 0) { rd[t>>6] = d; rx[t>>6] = nx; rz[t>>6] = nz; }
    __syncthreads();

    float4 zs;
    zs.x = xv.x + (zv.x - xv.x);
    zs.y = xv.y + (zv.y - xv.y);
    zs.z = xv.z + (zv.z - xv.z);
    zs.w = xv.w + (zv.w - xv.w);
    ((float4*)o_zq)[(size_t)tok * 256 + t] = zv;
    ((float4*)o_zst)[(size_t)tok * 256 + t] = zs;

    if (t == 0) {
        float D  = rd[0]+rd[1]+rd[2]+rd[3];
        float NX = rx[0]+rx[1]+rx[2]+rx[3];
        float NZ = rz[0]+rz[1]+rz[2]+rz[3];
        float cs = D / (fmaxf(sqrtf(NX), 1e-8f) * fmaxf(sqrtf(NZ), 1e-8f));
        o_idx[tok]  = (float)col;
        perTok[tok] = 1.f - cs;
    }
}

// ---- K4: single-block reduction of per-token losses + finalize scalars ----
__global__ __launch_bounds__(256) void k_final(
    const float* __restrict__ perTok,
    const float* __restrict__ o_idx,
    float* __restrict__ o_scal)
{
    const int t = threadIdx.x;
    float cs = 0.f, vs = 0.f, vc = 0.f;
    for (int i = t; i < N_TOK; i += 256) {
        float p = perTok[i];
        cs += p;
        if (o_idx[i] >= (float)N_SEM) { vs += p; vc += 1.f; }
    }
    #pragma unroll
    for (int off = 32; off > 0; off >>= 1) {
        cs += __shfl_xor(cs, off);
        vs += __shfl_xor(vs, off);
        vc += __shfl_xor(vc, off);
    }
    __shared__ float r0[4], r1[4], r2[4];
    if ((t & 63) == 0) { r0[t>>6] = cs; r1[t>>6] = vs; r2[t>>6] = vc; }
    __syncthreads();
    if (t == 0) {
        float C = r0[0]+r0[1]+r0[2]+r0[3];
        float V = r1[0]+r1[1]+r1[2]+r1[3];
        float K = r2[0]+r2[1]+r2[2]+r2[3];
        float commit = C / (float)N_TOK;
        float vq     = V / (K + 1e-6f);
        o_scal[0] = vq;
        o_scal[1] = commit;
        o_scal[2] = vq + 0.25f * commit;
    }
}

extern "C" void kernel_launch(void* const* d_in, const int* in_sizes, int n_in,
                              void* d_out, int out_size, void* d_ws, size_t ws_size,
                              hipStream_t stream) {
    const float* x   = (const float*)d_in[0];   // [8192,1024] fp32
    const float* sem = (const float*)d_in[1];   // [8192,1024] fp32
    const float* lrn = (const float*)d_in[2];   // [128,1024]  fp32

    // ws: invnx[8192] | invnb[8320] | keys[8192] u64 | perTok[8192] | lrn hi/lo
    // total ~692 KB
    float* invnx = (float*)d_ws;
    float* invnb = invnx + N_TOK;
    unsigned long long* keys = (unsigned long long*)(invnb + N_CODE); // byte 66048, 8-aligned
    float* perTok = (float*)(keys + N_TOK);     // byte 131584
    f16* lrnHi = (f16*)(perTok + N_TOK);        // byte 164352, 16-aligned
    f16* lrnLo = lrnHi + (size_t)N_LEARN * DIM;

    float* out      = (float*)d_out;
    float* o_logits = out;                                  // 68,157,440 f32
    float* o_idx    = o_logits + (size_t)N_TOK * N_CODE;    // 8,192
    float* o_zq     = o_idx + N_TOK;                        // 8,388,608
    float* o_zst    = o_zq + (size_t)N_TOK * DIM;           // 8,388,608
    float* o_scal   = o_zst + (size_t)N_TOK * DIM;          // 3

    // split scratch aliased onto z_q / z_q_st (overwritten later by k_epilogue)
    f16* xHi   = (f16*)o_zq;                    // 8192*1024 f16
    f16* xLo   = xHi + (size_t)N_TOK * DIM;     //  = exactly o_zq's 33.55 MB
    f16* semHi = (f16*)o_zst;
    f16* semLo = semHi + (size_t)N_SEM * DIM;   //  = exactly o_zst's 33.55 MB

    k_init<<<(N_TOK + 255) / 256, 256, 0, stream>>>(keys);
    k_norm_split<<<N_TOK,   256, 0, stream>>>(x,   invnx,         xHi,   xLo);
    k_norm_split<<<N_SEM,   256, 0, stream>>>(sem, invnb,         semHi, semLo);
    k_norm_split<<<N_LEARN, 256, 0, stream>>>(lrn, invnb + N_SEM, lrnHi, lrnLo);

    dim3 g2(N_TOK / BM, N_CODE / BN);   // 64 x 65
    k_gemm_mfma<<<g2, 256, 0, stream>>>(xHi, xLo, semHi, semLo, lrnHi, lrnLo,
                                        invnx, invnb, o_logits, keys);

    k_epilogue<<<N_TOK, 256, 0, stream>>>(x, sem, lrn, invnx, invnb, keys,
                                          o_idx, o_zq, o_zst, perTok);
    k_final<<<1, 256, 0, stream>>>(perTok, o_idx, o_scal);
}